// Round 8
// baseline (373.107 us; speedup 1.0000x reference)
//
#include <hip/hip_runtime.h>
#include <hip/hip_bf16.h>

#define NN 100000
#define EE 1600000
#define LN_EPS 1e-5f

__device__ __forceinline__ float bf_lo(unsigned u) {
  union { unsigned i; float f; } c; c.i = u << 16; return c.f;
}
__device__ __forceinline__ float bf_hi(unsigned u) {
  union { unsigned i; float f; } c; c.i = u & 0xffff0000u; return c.f;
}
__device__ __forceinline__ float us_bf(unsigned short u) {
  union { unsigned i; float f; } c; c.i = ((unsigned)u) << 16; return c.f;
}
__device__ __forceinline__ unsigned short f2bf(float f) {
  union { float f; unsigned i; } c; c.f = f;
  unsigned b = c.i + 0x7fffu + ((c.i >> 16) & 1u);
  return (unsigned short)(b >> 16);
}
__device__ __forceinline__ float lrelu02(float v) { return v >= 0.f ? v : 0.2f * v; }

// ---------------- K0: detect int64 vs int32 edge_index ----------------
__global__ void k_detect(const void* __restrict__ ei, int* __restrict__ flag) {
  if (threadIdx.x == 0 && blockIdx.x == 0) {
    const unsigned long long* p = (const unsigned long long*)ei;
    int ok = 1;
    for (int i = 0; i < 256; ++i)
      if (p[i] >= (unsigned long long)NN) { ok = 0; break; }
    *flag = ok;  // 1 => int64, 0 => int32
  }
}

// ---------------- K1: normalize edge_index to int32 + dst histogram (x2 vec) -----
__global__ __launch_bounds__(256) void k_convert_hist(const void* __restrict__ ei,
                                                      const int* __restrict__ flag,
                                                      int* __restrict__ idx32,
                                                      int* __restrict__ counts) {
  int gid = blockIdx.x * 256 + threadIdx.x;
  if (gid >= EE) return;  // handles elements 2*gid, 2*gid+1 of [0, 2*EE)
  int i0 = gid * 2;
  int v0, v1;
  if (*flag) {
    longlong2 lv = *(const longlong2*)((const long long*)ei + i0);
    v0 = (int)lv.x; v1 = (int)lv.y;
  } else {
    int2 iv = *(const int2*)((const int*)ei + i0);
    v0 = iv.x; v1 = iv.y;
  }
  *(int2*)(idx32 + i0) = make_int2(v0, v1);
  if (i0 >= EE) {
    atomicAdd(&counts[v0], 1);
    atomicAdd(&counts[v1], 1);
  }
}

// ---------------- K2: x = P@W (bf16 out), a_src/a_dst (bf16 out) ----------------
__global__ __launch_bounds__(512) void k_gemm_node(
    const float* __restrict__ P, const float* __restrict__ W,
    const float* __restrict__ attS, const float* __restrict__ attD,
    unsigned* __restrict__ xb, unsigned short* __restrict__ a_srcb,
    unsigned short* __restrict__ a_dstb, int nrows) {
  __shared__ float Rl[32 * 66];
  int t = threadIdx.x;
  int w = __builtin_amdgcn_readfirstlane(t >> 6);
  int l = t & 63;
  int rb = blockIdx.x * 64;
  int cb = w * 16;
  float acc[16];
#pragma unroll
  for (int j = 0; j < 16; ++j) acc[j] = 0.f;

  for (int kc = 0; kc < 4; ++kc) {
    __syncthreads();
    {
      int row = t >> 3;
      int k0 = (t & 7) * 4;
      int grow = rb + row;
      float4 v = make_float4(0.f, 0.f, 0.f, 0.f);
      if (grow < nrows)
        v = *(const float4*)(P + (size_t)grow * 128 + kc * 32 + k0);
      Rl[(k0 + 0) * 66 + row] = v.x;
      Rl[(k0 + 1) * 66 + row] = v.y;
      Rl[(k0 + 2) * 66 + row] = v.z;
      Rl[(k0 + 3) * 66 + row] = v.w;
    }
    __syncthreads();
    const float* Wp = W + (size_t)(kc * 32) * 128 + cb;
#pragma unroll 8
    for (int k = 0; k < 32; ++k) {
      float rv = Rl[k * 66 + l];
#pragma unroll
      for (int j = 0; j < 16; ++j) acc[j] = fmaf(rv, Wp[k * 128 + j], acc[j]);
    }
  }
  int row = rb + l;
  if (row < nrows) {
    float sa = 0.f, sd = 0.f;
#pragma unroll
    for (int j = 0; j < 16; ++j) {
      sa = fmaf(acc[j], attS[cb + j], sa);
      sd = fmaf(acc[j], attD[cb + j], sd);
    }
    a_srcb[(size_t)row * 8 + w] = f2bf(sa);
    a_dstb[(size_t)row * 8 + w] = f2bf(sd);
    unsigned pk[8];
#pragma unroll
    for (int m = 0; m < 8; ++m)
      pk[m] = (unsigned)f2bf(acc[2 * m]) | ((unsigned)f2bf(acc[2 * m + 1]) << 16);
    unsigned* xo = xb + (size_t)row * 64 + cb / 2;
    *(uint4*)(xo) = make_uint4(pk[0], pk[1], pk[2], pk[3]);
    *(uint4*)(xo + 4) = make_uint4(pk[4], pk[5], pk[6], pk[7]);
  }
}

// ---------------- K4: per-block sums ----------------
__global__ __launch_bounds__(256) void k_blocksum(const int* __restrict__ counts,
                                                  int* __restrict__ partials, int n) {
  __shared__ int sm[256];
  int t = threadIdx.x;
  int gid = blockIdx.x * 256 + t;
  sm[t] = gid < n ? counts[gid] : 0;
  __syncthreads();
  for (int s = 128; s > 0; s >>= 1) {
    if (t < s) sm[t] += sm[t + s];
    __syncthreads();
  }
  if (t == 0) partials[blockIdx.x] = sm[0];
}

// ---------------- K5: exclusive scan of partials ----------------
__global__ __launch_bounds__(512) void k_scanpartials(int* __restrict__ partials, int nb) {
  __shared__ int sm[512];
  int t = threadIdx.x;
  int v = t < nb ? partials[t] : 0;
  sm[t] = v;
  __syncthreads();
  for (int off = 1; off < 512; off <<= 1) {
    int u = (t >= off) ? sm[t - off] : 0;
    __syncthreads();
    sm[t] += u;
    __syncthreads();
  }
  if (t < nb) partials[t] = sm[t] - v;
}

// ---------------- K6: final exclusive scan -> offsets, cursor ----------------
__global__ __launch_bounds__(256) void k_scanfinal(const int* __restrict__ counts,
                                                   const int* __restrict__ partials,
                                                   int* __restrict__ offsets,
                                                   int* __restrict__ cursor, int n) {
  __shared__ int sm[256];
  int t = threadIdx.x;
  int gid = blockIdx.x * 256 + t;
  int v = gid < n ? counts[gid] : 0;
  sm[t] = v;
  __syncthreads();
  for (int off = 1; off < 256; off <<= 1) {
    int u = (t >= off) ? sm[t - off] : 0;
    __syncthreads();
    sm[t] += u;
    __syncthreads();
  }
  int excl = partials[blockIdx.x] + sm[t] - v;
  if (gid < n) {
    offsets[gid] = excl;
    cursor[gid] = excl;
  }
  if (gid == n - 1) offsets[n] = excl + v;
}

// ---------------- K7: asum = a_src[sv]+a_edge -> sorted 32B rec {asum,sv,e,dv,0}
// 2 edges per thread; atomics issued before the FMA block.
__global__ __launch_bounds__(256) void k_edgeprep(
    const float* __restrict__ EA, const float* __restrict__ Wedge,
    const float* __restrict__ attE, const int* __restrict__ src,
    const int* __restrict__ dst, const unsigned short* __restrict__ a_srcb,
    int* __restrict__ cursor, unsigned* __restrict__ rec) {
  __shared__ float M[16][8];
  int t = threadIdx.x;
  if (t < 128) {
    int d = t >> 3, h = t & 7;
    float s = 0.f;
#pragma unroll
    for (int c = 0; c < 16; ++c)
      s = fmaf(Wedge[d * 128 + h * 16 + c], attE[h * 16 + c], s);
    M[d][h] = s;
  }
  __syncthreads();
  int gid = blockIdx.x * 256 + t;
  int i0 = gid * 2;
  if (i0 >= EE) return;
  int2 svs = *(const int2*)(src + i0);
  int2 dvs = *(const int2*)(dst + i0);
  // issue atomics early: their latency hides under the FMA block below
  int pos0 = atomicAdd(&cursor[dvs.x], 1);
  int pos1 = atomicAdd(&cursor[dvs.y], 1);
  uint4 as0 = *(const uint4*)(a_srcb + (unsigned)svs.x * 8);
  uint4 as1 = *(const uint4*)(a_srcb + (unsigned)svs.y * 8);
  float ea0[16], ea1[16];
  const float4* e4 = (const float4*)(EA + (size_t)i0 * 16);
#pragma unroll
  for (int i = 0; i < 4; ++i) {
    float4 v = e4[i];
    ea0[i * 4] = v.x; ea0[i * 4 + 1] = v.y; ea0[i * 4 + 2] = v.z; ea0[i * 4 + 3] = v.w;
  }
#pragma unroll
  for (int i = 0; i < 4; ++i) {
    float4 v = e4[4 + i];
    ea1[i * 4] = v.x; ea1[i * 4 + 1] = v.y; ea1[i * 4 + 2] = v.z; ea1[i * 4 + 3] = v.w;
  }
  unsigned asu0[4] = {as0.x, as0.y, as0.z, as0.w};
  unsigned asu1[4] = {as1.x, as1.y, as1.z, as1.w};
  unsigned pk0[4], pk1[4];
#pragma unroll
  for (int m = 0; m < 4; ++m) {
    float a0 = 0.f, a1 = 0.f, b0 = 0.f, b1 = 0.f;
#pragma unroll
    for (int d = 0; d < 16; ++d) {
      a0 = fmaf(ea0[d], M[d][2 * m], a0);
      a1 = fmaf(ea0[d], M[d][2 * m + 1], a1);
      b0 = fmaf(ea1[d], M[d][2 * m], b0);
      b1 = fmaf(ea1[d], M[d][2 * m + 1], b1);
    }
    a0 += bf_lo(asu0[m]); a1 += bf_hi(asu0[m]);
    b0 += bf_lo(asu1[m]); b1 += bf_hi(asu1[m]);
    pk0[m] = (unsigned)f2bf(a0) | ((unsigned)f2bf(a1) << 16);
    pk1[m] = (unsigned)f2bf(b0) | ((unsigned)f2bf(b1) << 16);
  }
  unsigned* rp0 = rec + (size_t)pos0 * 8;
  *(uint4*)(rp0) = make_uint4(pk0[0], pk0[1], pk0[2], pk0[3]);
  *(uint4*)(rp0 + 4) = make_uint4((unsigned)svs.x, (unsigned)i0, (unsigned)dvs.x, 0u);
  unsigned* rp1 = rec + (size_t)pos1 * 8;
  *(uint4*)(rp1) = make_uint4(pk1[0], pk1[1], pk1[2], pk1[3]);
  *(uint4*)(rp1 + 4) = make_uint4((unsigned)svs.y, (unsigned)(i0 + 1), (unsigned)dvs.y, 0u);
}

// ---------------- K8: fused alpha-recompute + softmax + aggregation + LN ----------
// one wave per node. Four 16-lane quarter-teams own interleaved edge sub-streams;
// lane owns 8 cols (c0 = 8*ql) via one uint4 load; head h = ql>>1.
// rec read is sequential; only xb is gathered. 4 edges in flight per team.
__global__ __launch_bounds__(512) void k_megaagg(
    const int* __restrict__ offsets, const unsigned* __restrict__ rec,
    const unsigned short* __restrict__ a_dstb, const unsigned* __restrict__ xb,
    const float* __restrict__ bias, const float* __restrict__ g,
    const float* __restrict__ b, float* __restrict__ node_out,
    float* __restrict__ inv_arr) {
  int w = threadIdx.x >> 6, l = threadIdx.x & 63;
  int n = blockIdx.x * 8 + w;
  if (n >= NN) return;
  int s = offsets[n], e = offsets[n + 1];
  int qt = l >> 4, ql = l & 15;
  int h = ql >> 1;
  int hsel = (ql >> 1) & 1;  // head's half within its packed word: h&1
  int hw = ql >> 2;          // u32 word index of head pair: h>>1
  float ad = us_bf(a_dstb[(unsigned)n * 8 + h]);
  float dn0 = 0.f, dn1 = 0.f, dn2 = 0.f, dn3 = 0.f;
  float acc[8] = {0.f, 0.f, 0.f, 0.f, 0.f, 0.f, 0.f, 0.f};
  int i = s + qt;
  for (; i + 12 < e; i += 16) {
    const unsigned* rA = rec + (size_t)i * 8;
    const unsigned* rB = rec + (size_t)(i + 4) * 8;
    const unsigned* rC = rec + (size_t)(i + 8) * 8;
    const unsigned* rD = rec + (size_t)(i + 12) * 8;
    unsigned auA = rA[hw]; int svA = (int)rA[4];
    unsigned auB = rB[hw]; int svB = (int)rB[4];
    unsigned auC = rC[hw]; int svC = (int)rC[4];
    unsigned auD = rD[hw]; int svD = (int)rD[4];
    uint4 xA = *(const uint4*)(xb + (unsigned)svA * 64 + ql * 4);
    uint4 xB = *(const uint4*)(xb + (unsigned)svB * 64 + ql * 4);
    uint4 xC = *(const uint4*)(xb + (unsigned)svC * 64 + ql * 4);
    uint4 xD = *(const uint4*)(xb + (unsigned)svD * 64 + ql * 4);
    float aA = hsel ? bf_hi(auA) : bf_lo(auA);
    float aB = hsel ? bf_hi(auB) : bf_lo(auB);
    float aC = hsel ? bf_hi(auC) : bf_lo(auC);
    float aD = hsel ? bf_hi(auD) : bf_lo(auD);
    float eA = __expf(lrelu02(aA + ad));
    float eB = __expf(lrelu02(aB + ad));
    float eC = __expf(lrelu02(aC + ad));
    float eD = __expf(lrelu02(aD + ad));
    dn0 += eA; dn1 += eB; dn2 += eC; dn3 += eD;
    acc[0] = fmaf(eA, bf_lo(xA.x), acc[0]); acc[1] = fmaf(eA, bf_hi(xA.x), acc[1]);
    acc[2] = fmaf(eA, bf_lo(xA.y), acc[2]); acc[3] = fmaf(eA, bf_hi(xA.y), acc[3]);
    acc[4] = fmaf(eA, bf_lo(xA.z), acc[4]); acc[5] = fmaf(eA, bf_hi(xA.z), acc[5]);
    acc[6] = fmaf(eA, bf_lo(xA.w), acc[6]); acc[7] = fmaf(eA, bf_hi(xA.w), acc[7]);
    acc[0] = fmaf(eB, bf_lo(xB.x), acc[0]); acc[1] = fmaf(eB, bf_hi(xB.x), acc[1]);
    acc[2] = fmaf(eB, bf_lo(xB.y), acc[2]); acc[3] = fmaf(eB, bf_hi(xB.y), acc[3]);
    acc[4] = fmaf(eB, bf_lo(xB.z), acc[4]); acc[5] = fmaf(eB, bf_hi(xB.z), acc[5]);
    acc[6] = fmaf(eB, bf_lo(xB.w), acc[6]); acc[7] = fmaf(eB, bf_hi(xB.w), acc[7]);
    acc[0] = fmaf(eC, bf_lo(xC.x), acc[0]); acc[1] = fmaf(eC, bf_hi(xC.x), acc[1]);
    acc[2] = fmaf(eC, bf_lo(xC.y), acc[2]); acc[3] = fmaf(eC, bf_hi(xC.y), acc[3]);
    acc[4] = fmaf(eC, bf_lo(xC.z), acc[4]); acc[5] = fmaf(eC, bf_hi(xC.z), acc[5]);
    acc[6] = fmaf(eC, bf_lo(xC.w), acc[6]); acc[7] = fmaf(eC, bf_hi(xC.w), acc[7]);
    acc[0] = fmaf(eD, bf_lo(xD.x), acc[0]); acc[1] = fmaf(eD, bf_hi(xD.x), acc[1]);
    acc[2] = fmaf(eD, bf_lo(xD.y), acc[2]); acc[3] = fmaf(eD, bf_hi(xD.y), acc[3]);
    acc[4] = fmaf(eD, bf_lo(xD.z), acc[4]); acc[5] = fmaf(eD, bf_hi(xD.z), acc[5]);
    acc[6] = fmaf(eD, bf_lo(xD.w), acc[6]); acc[7] = fmaf(eD, bf_hi(xD.w), acc[7]);
  }
  for (; i < e; i += 4) {
    const unsigned* rA = rec + (size_t)i * 8;
    unsigned auA = rA[hw]; int svA = (int)rA[4];
    uint4 xA = *(const uint4*)(xb + (unsigned)svA * 64 + ql * 4);
    float aA = hsel ? bf_hi(auA) : bf_lo(auA);
    float eA = __expf(lrelu02(aA + ad));
    dn0 += eA;
    acc[0] = fmaf(eA, bf_lo(xA.x), acc[0]); acc[1] = fmaf(eA, bf_hi(xA.x), acc[1]);
    acc[2] = fmaf(eA, bf_lo(xA.y), acc[2]); acc[3] = fmaf(eA, bf_hi(xA.y), acc[3]);
    acc[4] = fmaf(eA, bf_lo(xA.z), acc[4]); acc[5] = fmaf(eA, bf_hi(xA.z), acc[5]);
    acc[6] = fmaf(eA, bf_lo(xA.w), acc[6]); acc[7] = fmaf(eA, bf_hi(xA.w), acc[7]);
  }
  float den = (dn0 + dn1) + (dn2 + dn3);
  den += __shfl_xor(den, 16);
  den += __shfl_xor(den, 32);
#pragma unroll
  for (int j = 0; j < 8; ++j) {
    acc[j] += __shfl_xor(acc[j], 16);
    acc[j] += __shfl_xor(acc[j], 32);
  }
  float inv = 1.f / (den + 1e-16f);
  if (qt == 0 && (ql & 1) == 0) inv_arr[(unsigned)n * 8 + h] = inv;
  int c0 = ql * 8;
  float4 bv0 = *(const float4*)(bias + c0);
  float4 bv1 = *(const float4*)(bias + c0 + 4);
  acc[0] = acc[0] * inv + bv0.x;
  acc[1] = acc[1] * inv + bv0.y;
  acc[2] = acc[2] * inv + bv0.z;
  acc[3] = acc[3] * inv + bv0.w;
  acc[4] = acc[4] * inv + bv1.x;
  acc[5] = acc[5] * inv + bv1.y;
  acc[6] = acc[6] * inv + bv1.z;
  acc[7] = acc[7] * inv + bv1.w;
  float sum = ((acc[0] + acc[1]) + (acc[2] + acc[3])) +
              ((acc[4] + acc[5]) + (acc[6] + acc[7]));
#pragma unroll
  for (int off = 1; off < 64; off <<= 1) sum += __shfl_xor(sum, off);
  float mu = sum * (1.f / 512.f);  // cols duplicated across 4 quarter-teams
  float d[8], ss = 0.f;
#pragma unroll
  for (int j = 0; j < 8; ++j) { d[j] = acc[j] - mu; ss += d[j] * d[j]; }
#pragma unroll
  for (int off = 1; off < 64; off <<= 1) ss += __shfl_xor(ss, off);
  float r = rsqrtf(ss * (1.f / 512.f) + LN_EPS);
  if (qt == 0) {
    float4 gv0 = *(const float4*)(g + c0);
    float4 gv1 = *(const float4*)(g + c0 + 4);
    float4 bb0 = *(const float4*)(b + c0);
    float4 bb1 = *(const float4*)(b + c0 + 4);
    float y[8];
    y[0] = d[0] * r * gv0.x + bb0.x;
    y[1] = d[1] * r * gv0.y + bb0.y;
    y[2] = d[2] * r * gv0.z + bb0.z;
    y[3] = d[3] * r * gv0.w + bb0.w;
    y[4] = d[4] * r * gv1.x + bb1.x;
    y[5] = d[5] * r * gv1.y + bb1.y;
    y[6] = d[6] * r * gv1.z + bb1.z;
    y[7] = d[7] * r * gv1.w + bb1.w;
#pragma unroll
    for (int j = 0; j < 8; ++j) y[j] = y[j] >= 0.f ? y[j] : 0.01f * y[j];
    float* no = node_out + (size_t)n * 128 + c0;
    *(float4*)(no) = make_float4(y[0], y[1], y[2], y[3]);
    *(float4*)(no + 4) = make_float4(y[4], y[5], y[6], y[7]);
  }
}

// ---------------- K9: edge out — sorted-order walk over rec, scatter edge_out[e] --
// rec read sequential; a_dstb/inv gathers are segment-local (consecutive same dv).
__global__ __launch_bounds__(256) void k_edgeout(
    const unsigned* __restrict__ rec, const unsigned short* __restrict__ a_dstb,
    const float* __restrict__ inv_arr, const float* __restrict__ g,
    const float* __restrict__ b, const float* __restrict__ ew,
    const float* __restrict__ eb, float* __restrict__ edge_out) {
  int gid = blockIdx.x * 256 + threadIdx.x;
  if (gid * 2 >= EE) return;
  float gl[8], bl[8], wl[8];
#pragma unroll
  for (int h = 0; h < 8; ++h) { gl[h] = g[h]; bl[h] = b[h]; wl[h] = ew[h]; }
  float ebv = eb[0];
#pragma unroll
  for (int u = 0; u < 2; ++u) {
    const unsigned* rp = rec + (size_t)(gid * 2 + u) * 8;
    uint4 as4 = *(const uint4*)(rp);
    uint4 hi4 = *(const uint4*)(rp + 4);
    int e = (int)hi4.y;
    int dv = (int)hi4.z;
    uint4 ad4 = *(const uint4*)(a_dstb + (unsigned)dv * 8);
    const float4* iv4 = (const float4*)(inv_arr + (unsigned)dv * 8);
    float4 iv0 = iv4[0], iv1 = iv4[1];
    float iv[8] = {iv0.x, iv0.y, iv0.z, iv0.w, iv1.x, iv1.y, iv1.z, iv1.w};
    unsigned asu[4] = {as4.x, as4.y, as4.z, as4.w};
    unsigned adu[4] = {ad4.x, ad4.y, ad4.z, ad4.w};
    float p[8];
#pragma unroll
    for (int m = 0; m < 4; ++m) {
      float a0 = lrelu02(bf_lo(asu[m]) + bf_lo(adu[m]));
      float a1 = lrelu02(bf_hi(asu[m]) + bf_hi(adu[m]));
      p[2 * m] = __expf(a0) * iv[2 * m];
      p[2 * m + 1] = __expf(a1) * iv[2 * m + 1];
    }
    float mu = 0.f;
#pragma unroll
    for (int h = 0; h < 8; ++h) mu += p[h];
    mu *= 0.125f;
    float var = 0.f;
#pragma unroll
    for (int h = 0; h < 8; ++h) { float dd = p[h] - mu; var += dd * dd; }
    var *= 0.125f;
    float r = rsqrtf(var + LN_EPS);
    float o = ebv;
#pragma unroll
    for (int h = 0; h < 8; ++h)
      o += ((p[h] - mu) * r * gl[h] + bl[h]) * wl[h];
    edge_out[e] = fmaxf(o, 0.f);
  }
}

extern "C" void kernel_launch(void* const* d_in, const int* in_sizes, int n_in,
                              void* d_out, int out_size, void* d_ws, size_t ws_size,
                              hipStream_t stream) {
  const void* edge_index = d_in[0];
  const float* point_attr = (const float*)d_in[1];
  const float* edge_attr = (const float*)d_in[2];
  const float* W = (const float*)d_in[3];
  const float* att_src = (const float*)d_in[4];
  const float* att_dst = (const float*)d_in[5];
  const float* W_edge = (const float*)d_in[6];
  const float* att_edge = (const float*)d_in[7];
  const float* bias = (const float*)d_in[8];
  const float* ln_node_g = (const float*)d_in[9];
  const float* ln_node_b = (const float*)d_in[10];
  const float* ln_edge_g = (const float*)d_in[11];
  const float* ln_edge_b = (const float*)d_in[12];
  const float* edge_w = (const float*)d_in[13];
  const float* edge_b = (const float*)d_in[14];

  char* wsb = (char*)d_ws;
  size_t o = 0;
  auto take = [&](size_t bytes) -> void* {
    void* p = wsb + o;
    o += (bytes + 255) & ~(size_t)255;
    return p;
  };
  int* flag = (int*)take(4);
  int* idx32 = (int*)take((size_t)2 * EE * 4);
  unsigned* xb = (unsigned*)take((size_t)NN * 128 * 2);
  unsigned short* a_srcb = (unsigned short*)take((size_t)NN * 8 * 2);
  unsigned short* a_dstb = (unsigned short*)take((size_t)NN * 8 * 2);
  int* counts = (int*)take((size_t)NN * 4);
  int* offsets = (int*)take((size_t)(NN + 1) * 4);
  int* cursor = (int*)take((size_t)NN * 4);
  int* partials = (int*)take(512 * 4);
  unsigned* rec = (unsigned*)take((size_t)EE * 32);     // 32 B sorted records
  float* inv_arr = (float*)take((size_t)NN * 8 * 4);

  const int* srcp = idx32;
  const int* dstp = idx32 + EE;
  float* node_out = (float*)d_out;
  float* edge_out = node_out + (size_t)NN * 128;

  int nb_scan = (NN + 255) / 256;  // 391

  hipMemsetAsync(counts, 0, (size_t)NN * 4, stream);

  k_detect<<<1, 64, 0, stream>>>(edge_index, flag);
  k_convert_hist<<<(EE + 255) / 256, 256, 0, stream>>>(edge_index, flag, idx32, counts);
  k_gemm_node<<<(NN + 63) / 64, 512, 0, stream>>>(point_attr, W, att_src, att_dst,
                                                  xb, a_srcb, a_dstb, NN);
  k_blocksum<<<nb_scan, 256, 0, stream>>>(counts, partials, NN);
  k_scanpartials<<<1, 512, 0, stream>>>(partials, nb_scan);
  k_scanfinal<<<nb_scan, 256, 0, stream>>>(counts, partials, offsets, cursor, NN);
  k_edgeprep<<<(EE / 2 + 255) / 256, 256, 0, stream>>>(edge_attr, W_edge, att_edge,
                                                       srcp, dstp, a_srcb, cursor, rec);
  k_megaagg<<<(NN + 7) / 8, 512, 0, stream>>>(offsets, rec, a_dstb, xb, bias,
                                              ln_node_g, ln_node_b, node_out, inv_arr);
  k_edgeout<<<(EE / 2 + 255) / 256, 256, 0, stream>>>(rec, a_dstb, inv_arr,
                                                      ln_edge_g, ln_edge_b, edge_w,
                                                      edge_b, edge_out);
}

// Round 9
// 369.348 us; speedup vs baseline: 1.0102x; 1.0102x over previous
//
#include <hip/hip_runtime.h>
#include <hip/hip_bf16.h>

#define NN 100000
#define EE 1600000
#define LN_EPS 1e-5f

__device__ __forceinline__ float bf_lo(unsigned u) {
  union { unsigned i; float f; } c; c.i = u << 16; return c.f;
}
__device__ __forceinline__ float bf_hi(unsigned u) {
  union { unsigned i; float f; } c; c.i = u & 0xffff0000u; return c.f;
}
__device__ __forceinline__ float us_bf(unsigned short u) {
  union { unsigned i; float f; } c; c.i = ((unsigned)u) << 16; return c.f;
}
__device__ __forceinline__ unsigned short f2bf(float f) {
  union { float f; unsigned i; } c; c.f = f;
  unsigned b = c.i + 0x7fffu + ((c.i >> 16) & 1u);
  return (unsigned short)(b >> 16);
}
__device__ __forceinline__ float lrelu02(float v) { return v >= 0.f ? v : 0.2f * v; }

// ---------------- K0: detect int64 vs int32 edge_index ----------------
__global__ void k_detect(const void* __restrict__ ei, int* __restrict__ flag) {
  if (threadIdx.x == 0 && blockIdx.x == 0) {
    const unsigned long long* p = (const unsigned long long*)ei;
    int ok = 1;
    for (int i = 0; i < 256; ++i)
      if (p[i] >= (unsigned long long)NN) { ok = 0; break; }
    *flag = ok;  // 1 => int64, 0 => int32
  }
}

// ------- K1: normalize edge_index to int32 + dst histogram + per-edge rank -------
// rank[e] = position of edge e within its dst segment (atomicAdd return value).
__global__ __launch_bounds__(256) void k_convert_hist(const void* __restrict__ ei,
                                                      const int* __restrict__ flag,
                                                      int* __restrict__ idx32,
                                                      int* __restrict__ counts,
                                                      int* __restrict__ rank) {
  int gid = blockIdx.x * 256 + threadIdx.x;
  if (gid >= EE) return;  // handles elements 2*gid, 2*gid+1 of [0, 2*EE)
  int i0 = gid * 2;
  int v0, v1;
  if (*flag) {
    longlong2 lv = *(const longlong2*)((const long long*)ei + i0);
    v0 = (int)lv.x; v1 = (int)lv.y;
  } else {
    int2 iv = *(const int2*)((const int*)ei + i0);
    v0 = iv.x; v1 = iv.y;
  }
  *(int2*)(idx32 + i0) = make_int2(v0, v1);
  if (i0 >= EE) {
    int r0 = atomicAdd(&counts[v0], 1);
    int r1 = atomicAdd(&counts[v1], 1);
    *(int2*)(rank + (i0 - EE)) = make_int2(r0, r1);
  }
}

// ---------------- K2: x = P@W (bf16 out), a_src/a_dst (bf16 out) ----------------
__global__ __launch_bounds__(512) void k_gemm_node(
    const float* __restrict__ P, const float* __restrict__ W,
    const float* __restrict__ attS, const float* __restrict__ attD,
    unsigned* __restrict__ xb, unsigned short* __restrict__ a_srcb,
    unsigned short* __restrict__ a_dstb, int nrows) {
  __shared__ float Rl[32 * 66];
  int t = threadIdx.x;
  int w = __builtin_amdgcn_readfirstlane(t >> 6);
  int l = t & 63;
  int rb = blockIdx.x * 64;
  int cb = w * 16;
  float acc[16];
#pragma unroll
  for (int j = 0; j < 16; ++j) acc[j] = 0.f;

  for (int kc = 0; kc < 4; ++kc) {
    __syncthreads();
    {
      int row = t >> 3;
      int k0 = (t & 7) * 4;
      int grow = rb + row;
      float4 v = make_float4(0.f, 0.f, 0.f, 0.f);
      if (grow < nrows)
        v = *(const float4*)(P + (size_t)grow * 128 + kc * 32 + k0);
      Rl[(k0 + 0) * 66 + row] = v.x;
      Rl[(k0 + 1) * 66 + row] = v.y;
      Rl[(k0 + 2) * 66 + row] = v.z;
      Rl[(k0 + 3) * 66 + row] = v.w;
    }
    __syncthreads();
    const float* Wp = W + (size_t)(kc * 32) * 128 + cb;
#pragma unroll 8
    for (int k = 0; k < 32; ++k) {
      float rv = Rl[k * 66 + l];
#pragma unroll
      for (int j = 0; j < 16; ++j) acc[j] = fmaf(rv, Wp[k * 128 + j], acc[j]);
    }
  }
  int row = rb + l;
  if (row < nrows) {
    float sa = 0.f, sd = 0.f;
#pragma unroll
    for (int j = 0; j < 16; ++j) {
      sa = fmaf(acc[j], attS[cb + j], sa);
      sd = fmaf(acc[j], attD[cb + j], sd);
    }
    a_srcb[(size_t)row * 8 + w] = f2bf(sa);
    a_dstb[(size_t)row * 8 + w] = f2bf(sd);
    unsigned pk[8];
#pragma unroll
    for (int m = 0; m < 8; ++m)
      pk[m] = (unsigned)f2bf(acc[2 * m]) | ((unsigned)f2bf(acc[2 * m + 1]) << 16);
    unsigned* xo = xb + (size_t)row * 64 + cb / 2;
    *(uint4*)(xo) = make_uint4(pk[0], pk[1], pk[2], pk[3]);
    *(uint4*)(xo + 4) = make_uint4(pk[4], pk[5], pk[6], pk[7]);
  }
}

// ---------------- K4: per-block sums ----------------
__global__ __launch_bounds__(256) void k_blocksum(const int* __restrict__ counts,
                                                  int* __restrict__ partials, int n) {
  __shared__ int sm[256];
  int t = threadIdx.x;
  int gid = blockIdx.x * 256 + t;
  sm[t] = gid < n ? counts[gid] : 0;
  __syncthreads();
  for (int s = 128; s > 0; s >>= 1) {
    if (t < s) sm[t] += sm[t + s];
    __syncthreads();
  }
  if (t == 0) partials[blockIdx.x] = sm[0];
}

// ---------------- K5: exclusive scan of partials ----------------
__global__ __launch_bounds__(512) void k_scanpartials(int* __restrict__ partials, int nb) {
  __shared__ int sm[512];
  int t = threadIdx.x;
  int v = t < nb ? partials[t] : 0;
  sm[t] = v;
  __syncthreads();
  for (int off = 1; off < 512; off <<= 1) {
    int u = (t >= off) ? sm[t - off] : 0;
    __syncthreads();
    sm[t] += u;
    __syncthreads();
  }
  if (t < nb) partials[t] = sm[t] - v;
}

// ---------------- K6: final exclusive scan -> offsets ----------------
__global__ __launch_bounds__(256) void k_scanfinal(const int* __restrict__ counts,
                                                   const int* __restrict__ partials,
                                                   int* __restrict__ offsets, int n) {
  __shared__ int sm[256];
  int t = threadIdx.x;
  int gid = blockIdx.x * 256 + t;
  int v = gid < n ? counts[gid] : 0;
  sm[t] = v;
  __syncthreads();
  for (int off = 1; off < 256; off <<= 1) {
    int u = (t >= off) ? sm[t - off] : 0;
    __syncthreads();
    sm[t] += u;
    __syncthreads();
  }
  int excl = partials[blockIdx.x] + sm[t] - v;
  if (gid < n) offsets[gid] = excl;
  if (gid == n - 1) offsets[n] = excl + v;
}

// ------- K7: asum = a_src[sv]+a_edge -> sorted 32B rec at offsets[dv]+rank[e] -----
// No atomic: position precomputed. 1 edge/thread for max TLP.
__global__ __launch_bounds__(256) void k_edgeprep(
    const float* __restrict__ EA, const float* __restrict__ Wedge,
    const float* __restrict__ attE, const int* __restrict__ src,
    const int* __restrict__ dst, const unsigned short* __restrict__ a_srcb,
    const int* __restrict__ offsets, const int* __restrict__ rank,
    unsigned* __restrict__ rec) {
  __shared__ float M[16][8];
  int t = threadIdx.x;
  if (t < 128) {
    int d = t >> 3, h = t & 7;
    float s = 0.f;
#pragma unroll
    for (int c = 0; c < 16; ++c)
      s = fmaf(Wedge[d * 128 + h * 16 + c], attE[h * 16 + c], s);
    M[d][h] = s;
  }
  __syncthreads();
  int e = blockIdx.x * 256 + t;
  if (e >= EE) return;
  int sv = src[e], dv = dst[e];
  int rk = rank[e];
  int off = offsets[dv];          // 4 B gather from 400 KB (L2-resident)
  uint4 as4 = *(const uint4*)(a_srcb + (unsigned)sv * 8);
  float ea[16];
  const float4* ea4 = (const float4*)(EA + (size_t)e * 16);
#pragma unroll
  for (int i = 0; i < 4; ++i) {
    float4 v = ea4[i];
    ea[i * 4] = v.x; ea[i * 4 + 1] = v.y; ea[i * 4 + 2] = v.z; ea[i * 4 + 3] = v.w;
  }
  unsigned asu[4] = {as4.x, as4.y, as4.z, as4.w};
  unsigned pk[4];
#pragma unroll
  for (int m = 0; m < 4; ++m) {
    float s0 = 0.f, s1 = 0.f;
#pragma unroll
    for (int d = 0; d < 16; ++d) {
      s0 = fmaf(ea[d], M[d][2 * m], s0);
      s1 = fmaf(ea[d], M[d][2 * m + 1], s1);
    }
    s0 += bf_lo(asu[m]);
    s1 += bf_hi(asu[m]);
    pk[m] = (unsigned)f2bf(s0) | ((unsigned)f2bf(s1) << 16);
  }
  int pos = off + rk;
  unsigned* rp = rec + (size_t)pos * 8;   // 32 B sector-aligned record
  *(uint4*)(rp) = make_uint4(pk[0], pk[1], pk[2], pk[3]);
  *(uint4*)(rp + 4) = make_uint4((unsigned)sv, (unsigned)e, (unsigned)dv, 0u);
}

// ---------------- K8: fused alpha-recompute + softmax + aggregation + LN ----------
// one wave per node. Four 16-lane quarter-teams own interleaved edge sub-streams;
// lane owns 8 cols (c0 = 8*ql) via one uint4 load; head h = ql>>1.
// rec read is sequential; only xb is gathered. 4 edges in flight per team.
__global__ __launch_bounds__(512) void k_megaagg(
    const int* __restrict__ offsets, const unsigned* __restrict__ rec,
    const unsigned short* __restrict__ a_dstb, const unsigned* __restrict__ xb,
    const float* __restrict__ bias, const float* __restrict__ g,
    const float* __restrict__ b, float* __restrict__ node_out,
    float* __restrict__ inv_arr) {
  int w = threadIdx.x >> 6, l = threadIdx.x & 63;
  int n = blockIdx.x * 8 + w;
  if (n >= NN) return;
  int s = offsets[n], e = offsets[n + 1];
  int qt = l >> 4, ql = l & 15;
  int h = ql >> 1;
  int hsel = (ql >> 1) & 1;  // head's half within its packed word: h&1
  int hw = ql >> 2;          // u32 word index of head pair: h>>1
  float ad = us_bf(a_dstb[(unsigned)n * 8 + h]);
  float dn0 = 0.f, dn1 = 0.f, dn2 = 0.f, dn3 = 0.f;
  float acc[8] = {0.f, 0.f, 0.f, 0.f, 0.f, 0.f, 0.f, 0.f};
  int i = s + qt;
  for (; i + 12 < e; i += 16) {
    const unsigned* rA = rec + (size_t)i * 8;
    const unsigned* rB = rec + (size_t)(i + 4) * 8;
    const unsigned* rC = rec + (size_t)(i + 8) * 8;
    const unsigned* rD = rec + (size_t)(i + 12) * 8;
    unsigned auA = rA[hw]; int svA = (int)rA[4];
    unsigned auB = rB[hw]; int svB = (int)rB[4];
    unsigned auC = rC[hw]; int svC = (int)rC[4];
    unsigned auD = rD[hw]; int svD = (int)rD[4];
    uint4 xA = *(const uint4*)(xb + (unsigned)svA * 64 + ql * 4);
    uint4 xB = *(const uint4*)(xb + (unsigned)svB * 64 + ql * 4);
    uint4 xC = *(const uint4*)(xb + (unsigned)svC * 64 + ql * 4);
    uint4 xD = *(const uint4*)(xb + (unsigned)svD * 64 + ql * 4);
    float aA = hsel ? bf_hi(auA) : bf_lo(auA);
    float aB = hsel ? bf_hi(auB) : bf_lo(auB);
    float aC = hsel ? bf_hi(auC) : bf_lo(auC);
    float aD = hsel ? bf_hi(auD) : bf_lo(auD);
    float eA = __expf(lrelu02(aA + ad));
    float eB = __expf(lrelu02(aB + ad));
    float eC = __expf(lrelu02(aC + ad));
    float eD = __expf(lrelu02(aD + ad));
    dn0 += eA; dn1 += eB; dn2 += eC; dn3 += eD;
    acc[0] = fmaf(eA, bf_lo(xA.x), acc[0]); acc[1] = fmaf(eA, bf_hi(xA.x), acc[1]);
    acc[2] = fmaf(eA, bf_lo(xA.y), acc[2]); acc[3] = fmaf(eA, bf_hi(xA.y), acc[3]);
    acc[4] = fmaf(eA, bf_lo(xA.z), acc[4]); acc[5] = fmaf(eA, bf_hi(xA.z), acc[5]);
    acc[6] = fmaf(eA, bf_lo(xA.w), acc[6]); acc[7] = fmaf(eA, bf_hi(xA.w), acc[7]);
    acc[0] = fmaf(eB, bf_lo(xB.x), acc[0]); acc[1] = fmaf(eB, bf_hi(xB.x), acc[1]);
    acc[2] = fmaf(eB, bf_lo(xB.y), acc[2]); acc[3] = fmaf(eB, bf_hi(xB.y), acc[3]);
    acc[4] = fmaf(eB, bf_lo(xB.z), acc[4]); acc[5] = fmaf(eB, bf_hi(xB.z), acc[5]);
    acc[6] = fmaf(eB, bf_lo(xB.w), acc[6]); acc[7] = fmaf(eB, bf_hi(xB.w), acc[7]);
    acc[0] = fmaf(eC, bf_lo(xC.x), acc[0]); acc[1] = fmaf(eC, bf_hi(xC.x), acc[1]);
    acc[2] = fmaf(eC, bf_lo(xC.y), acc[2]); acc[3] = fmaf(eC, bf_hi(xC.y), acc[3]);
    acc[4] = fmaf(eC, bf_lo(xC.z), acc[4]); acc[5] = fmaf(eC, bf_hi(xC.z), acc[5]);
    acc[6] = fmaf(eC, bf_lo(xC.w), acc[6]); acc[7] = fmaf(eC, bf_hi(xC.w), acc[7]);
    acc[0] = fmaf(eD, bf_lo(xD.x), acc[0]); acc[1] = fmaf(eD, bf_hi(xD.x), acc[1]);
    acc[2] = fmaf(eD, bf_lo(xD.y), acc[2]); acc[3] = fmaf(eD, bf_hi(xD.y), acc[3]);
    acc[4] = fmaf(eD, bf_lo(xD.z), acc[4]); acc[5] = fmaf(eD, bf_hi(xD.z), acc[5]);
    acc[6] = fmaf(eD, bf_lo(xD.w), acc[6]); acc[7] = fmaf(eD, bf_hi(xD.w), acc[7]);
  }
  for (; i < e; i += 4) {
    const unsigned* rA = rec + (size_t)i * 8;
    unsigned auA = rA[hw]; int svA = (int)rA[4];
    uint4 xA = *(const uint4*)(xb + (unsigned)svA * 64 + ql * 4);
    float aA = hsel ? bf_hi(auA) : bf_lo(auA);
    float eA = __expf(lrelu02(aA + ad));
    dn0 += eA;
    acc[0] = fmaf(eA, bf_lo(xA.x), acc[0]); acc[1] = fmaf(eA, bf_hi(xA.x), acc[1]);
    acc[2] = fmaf(eA, bf_lo(xA.y), acc[2]); acc[3] = fmaf(eA, bf_hi(xA.y), acc[3]);
    acc[4] = fmaf(eA, bf_lo(xA.z), acc[4]); acc[5] = fmaf(eA, bf_hi(xA.z), acc[5]);
    acc[6] = fmaf(eA, bf_lo(xA.w), acc[6]); acc[7] = fmaf(eA, bf_hi(xA.w), acc[7]);
  }
  float den = (dn0 + dn1) + (dn2 + dn3);
  den += __shfl_xor(den, 16);
  den += __shfl_xor(den, 32);
#pragma unroll
  for (int j = 0; j < 8; ++j) {
    acc[j] += __shfl_xor(acc[j], 16);
    acc[j] += __shfl_xor(acc[j], 32);
  }
  float inv = 1.f / (den + 1e-16f);
  if (qt == 0 && (ql & 1) == 0) inv_arr[(unsigned)n * 8 + h] = inv;
  int c0 = ql * 8;
  float4 bv0 = *(const float4*)(bias + c0);
  float4 bv1 = *(const float4*)(bias + c0 + 4);
  acc[0] = acc[0] * inv + bv0.x;
  acc[1] = acc[1] * inv + bv0.y;
  acc[2] = acc[2] * inv + bv0.z;
  acc[3] = acc[3] * inv + bv0.w;
  acc[4] = acc[4] * inv + bv1.x;
  acc[5] = acc[5] * inv + bv1.y;
  acc[6] = acc[6] * inv + bv1.z;
  acc[7] = acc[7] * inv + bv1.w;
  float sum = ((acc[0] + acc[1]) + (acc[2] + acc[3])) +
              ((acc[4] + acc[5]) + (acc[6] + acc[7]));
#pragma unroll
  for (int off = 1; off < 64; off <<= 1) sum += __shfl_xor(sum, off);
  float mu = sum * (1.f / 512.f);  // cols duplicated across 4 quarter-teams
  float d[8], ss = 0.f;
#pragma unroll
  for (int j = 0; j < 8; ++j) { d[j] = acc[j] - mu; ss += d[j] * d[j]; }
#pragma unroll
  for (int off = 1; off < 64; off <<= 1) ss += __shfl_xor(ss, off);
  float r = rsqrtf(ss * (1.f / 512.f) + LN_EPS);
  if (qt == 0) {
    float4 gv0 = *(const float4*)(g + c0);
    float4 gv1 = *(const float4*)(g + c0 + 4);
    float4 bb0 = *(const float4*)(b + c0);
    float4 bb1 = *(const float4*)(b + c0 + 4);
    float y[8];
    y[0] = d[0] * r * gv0.x + bb0.x;
    y[1] = d[1] * r * gv0.y + bb0.y;
    y[2] = d[2] * r * gv0.z + bb0.z;
    y[3] = d[3] * r * gv0.w + bb0.w;
    y[4] = d[4] * r * gv1.x + bb1.x;
    y[5] = d[5] * r * gv1.y + bb1.y;
    y[6] = d[6] * r * gv1.z + bb1.z;
    y[7] = d[7] * r * gv1.w + bb1.w;
#pragma unroll
    for (int j = 0; j < 8; ++j) y[j] = y[j] >= 0.f ? y[j] : 0.01f * y[j];
    float* no = node_out + (size_t)n * 128 + c0;
    *(float4*)(no) = make_float4(y[0], y[1], y[2], y[3]);
    *(float4*)(no + 4) = make_float4(y[4], y[5], y[6], y[7]);
  }
}

// ---------------- K9: edge out — sorted-order walk over rec, scatter edge_out[e] --
// rec read sequential; a_dstb/inv gathers are segment-local (consecutive same dv).
__global__ __launch_bounds__(256) void k_edgeout(
    const unsigned* __restrict__ rec, const unsigned short* __restrict__ a_dstb,
    const float* __restrict__ inv_arr, const float* __restrict__ g,
    const float* __restrict__ b, const float* __restrict__ ew,
    const float* __restrict__ eb, float* __restrict__ edge_out) {
  int gid = blockIdx.x * 256 + threadIdx.x;
  if (gid * 2 >= EE) return;
  float gl[8], bl[8], wl[8];
#pragma unroll
  for (int h = 0; h < 8; ++h) { gl[h] = g[h]; bl[h] = b[h]; wl[h] = ew[h]; }
  float ebv = eb[0];
#pragma unroll
  for (int u = 0; u < 2; ++u) {
    const unsigned* rp = rec + (size_t)(gid * 2 + u) * 8;
    uint4 as4 = *(const uint4*)(rp);
    uint4 hi4 = *(const uint4*)(rp + 4);
    int e = (int)hi4.y;
    int dv = (int)hi4.z;
    uint4 ad4 = *(const uint4*)(a_dstb + (unsigned)dv * 8);
    const float4* iv4 = (const float4*)(inv_arr + (unsigned)dv * 8);
    float4 iv0 = iv4[0], iv1 = iv4[1];
    float iv[8] = {iv0.x, iv0.y, iv0.z, iv0.w, iv1.x, iv1.y, iv1.z, iv1.w};
    unsigned asu[4] = {as4.x, as4.y, as4.z, as4.w};
    unsigned adu[4] = {ad4.x, ad4.y, ad4.z, ad4.w};
    float p[8];
#pragma unroll
    for (int m = 0; m < 4; ++m) {
      float a0 = lrelu02(bf_lo(asu[m]) + bf_lo(adu[m]));
      float a1 = lrelu02(bf_hi(asu[m]) + bf_hi(adu[m]));
      p[2 * m] = __expf(a0) * iv[2 * m];
      p[2 * m + 1] = __expf(a1) * iv[2 * m + 1];
    }
    float mu = 0.f;
#pragma unroll
    for (int h = 0; h < 8; ++h) mu += p[h];
    mu *= 0.125f;
    float var = 0.f;
#pragma unroll
    for (int h = 0; h < 8; ++h) { float dd = p[h] - mu; var += dd * dd; }
    var *= 0.125f;
    float r = rsqrtf(var + LN_EPS);
    float o = ebv;
#pragma unroll
    for (int h = 0; h < 8; ++h)
      o += ((p[h] - mu) * r * gl[h] + bl[h]) * wl[h];
    edge_out[e] = fmaxf(o, 0.f);
  }
}

extern "C" void kernel_launch(void* const* d_in, const int* in_sizes, int n_in,
                              void* d_out, int out_size, void* d_ws, size_t ws_size,
                              hipStream_t stream) {
  const void* edge_index = d_in[0];
  const float* point_attr = (const float*)d_in[1];
  const float* edge_attr = (const float*)d_in[2];
  const float* W = (const float*)d_in[3];
  const float* att_src = (const float*)d_in[4];
  const float* att_dst = (const float*)d_in[5];
  const float* W_edge = (const float*)d_in[6];
  const float* att_edge = (const float*)d_in[7];
  const float* bias = (const float*)d_in[8];
  const float* ln_node_g = (const float*)d_in[9];
  const float* ln_node_b = (const float*)d_in[10];
  const float* ln_edge_g = (const float*)d_in[11];
  const float* ln_edge_b = (const float*)d_in[12];
  const float* edge_w = (const float*)d_in[13];
  const float* edge_b = (const float*)d_in[14];

  char* wsb = (char*)d_ws;
  size_t o = 0;
  auto take = [&](size_t bytes) -> void* {
    void* p = wsb + o;
    o += (bytes + 255) & ~(size_t)255;
    return p;
  };
  int* flag = (int*)take(4);
  int* idx32 = (int*)take((size_t)2 * EE * 4);
  unsigned* xb = (unsigned*)take((size_t)NN * 128 * 2);
  unsigned short* a_srcb = (unsigned short*)take((size_t)NN * 8 * 2);
  unsigned short* a_dstb = (unsigned short*)take((size_t)NN * 8 * 2);
  int* counts = (int*)take((size_t)NN * 4);
  int* offsets = (int*)take((size_t)(NN + 1) * 4);
  int* rank = (int*)take((size_t)EE * 4);
  int* partials = (int*)take(512 * 4);
  unsigned* rec = (unsigned*)take((size_t)EE * 32);     // 32 B sorted records
  float* inv_arr = (float*)take((size_t)NN * 8 * 4);

  const int* srcp = idx32;
  const int* dstp = idx32 + EE;
  float* node_out = (float*)d_out;
  float* edge_out = node_out + (size_t)NN * 128;

  int nb_scan = (NN + 255) / 256;  // 391

  hipMemsetAsync(counts, 0, (size_t)NN * 4, stream);

  k_detect<<<1, 64, 0, stream>>>(edge_index, flag);
  k_convert_hist<<<(EE + 255) / 256, 256, 0, stream>>>(edge_index, flag, idx32,
                                                       counts, rank);
  k_gemm_node<<<(NN + 63) / 64, 512, 0, stream>>>(point_attr, W, att_src, att_dst,
                                                  xb, a_srcb, a_dstb, NN);
  k_blocksum<<<nb_scan, 256, 0, stream>>>(counts, partials, NN);
  k_scanpartials<<<1, 512, 0, stream>>>(partials, nb_scan);
  k_scanfinal<<<nb_scan, 256, 0, stream>>>(counts, partials, offsets, NN);
  k_edgeprep<<<(EE + 255) / 256, 256, 0, stream>>>(edge_attr, W_edge, att_edge,
                                                   srcp, dstp, a_srcb, offsets, rank,
                                                   rec);
  k_megaagg<<<(NN + 7) / 8, 512, 0, stream>>>(offsets, rec, a_dstb, xb, bias,
                                              ln_node_g, ln_node_b, node_out, inv_arr);
  k_edgeout<<<(EE / 2 + 255) / 256, 256, 0, stream>>>(rec, a_dstb, inv_arr,
                                                      ln_edge_g, ln_edge_b, edge_w,
                                                      edge_b, edge_out);
}

// Round 10
// 327.134 us; speedup vs baseline: 1.1405x; 1.1290x over previous
//
#include <hip/hip_runtime.h>
#include <hip/hip_bf16.h>

#define NN 100000
#define EE 1600000
#define LN_EPS 1e-5f

__device__ __forceinline__ float bf_lo(unsigned u) {
  union { unsigned i; float f; } c; c.i = u << 16; return c.f;
}
__device__ __forceinline__ float bf_hi(unsigned u) {
  union { unsigned i; float f; } c; c.i = u & 0xffff0000u; return c.f;
}
__device__ __forceinline__ float us_bf(unsigned short u) {
  union { unsigned i; float f; } c; c.i = ((unsigned)u) << 16; return c.f;
}
__device__ __forceinline__ unsigned short f2bf(float f) {
  union { float f; unsigned i; } c; c.f = f;
  unsigned b = c.i + 0x7fffu + ((c.i >> 16) & 1u);
  return (unsigned short)(b >> 16);
}
__device__ __forceinline__ float lrelu02(float v) { return v >= 0.f ? v : 0.2f * v; }

// ---------------- K0: detect int64 vs int32 edge_index ----------------
__global__ void k_detect(const void* __restrict__ ei, int* __restrict__ flag) {
  if (threadIdx.x == 0 && blockIdx.x == 0) {
    const unsigned long long* p = (const unsigned long long*)ei;
    int ok = 1;
    for (int i = 0; i < 256; ++i)
      if (p[i] >= (unsigned long long)NN) { ok = 0; break; }
    *flag = ok;  // 1 => int64, 0 => int32
  }
}

// ------- K1: normalize edge_index to int32 + dst histogram + per-edge rank -------
__global__ __launch_bounds__(256) void k_convert_hist(const void* __restrict__ ei,
                                                      const int* __restrict__ flag,
                                                      int* __restrict__ idx32,
                                                      int* __restrict__ counts,
                                                      int* __restrict__ rank) {
  int gid = blockIdx.x * 256 + threadIdx.x;
  if (gid >= EE) return;  // handles elements 2*gid, 2*gid+1 of [0, 2*EE)
  int i0 = gid * 2;
  int v0, v1;
  if (*flag) {
    longlong2 lv = *(const longlong2*)((const long long*)ei + i0);
    v0 = (int)lv.x; v1 = (int)lv.y;
  } else {
    int2 iv = *(const int2*)((const int*)ei + i0);
    v0 = iv.x; v1 = iv.y;
  }
  *(int2*)(idx32 + i0) = make_int2(v0, v1);
  if (i0 >= EE) {
    int r0 = atomicAdd(&counts[v0], 1);
    int r1 = atomicAdd(&counts[v1], 1);
    *(int2*)(rank + (i0 - EE)) = make_int2(r0, r1);
  }
}

// ---------------- K2: x = P@W (bf16 out), a_src/a_dst (bf16 out) ----------------
__global__ __launch_bounds__(512) void k_gemm_node(
    const float* __restrict__ P, const float* __restrict__ W,
    const float* __restrict__ attS, const float* __restrict__ attD,
    unsigned* __restrict__ xb, unsigned short* __restrict__ a_srcb,
    unsigned short* __restrict__ a_dstb, int nrows) {
  __shared__ float Rl[32 * 66];
  int t = threadIdx.x;
  int w = __builtin_amdgcn_readfirstlane(t >> 6);
  int l = t & 63;
  int rb = blockIdx.x * 64;
  int cb = w * 16;
  float acc[16];
#pragma unroll
  for (int j = 0; j < 16; ++j) acc[j] = 0.f;

  for (int kc = 0; kc < 4; ++kc) {
    __syncthreads();
    {
      int row = t >> 3;
      int k0 = (t & 7) * 4;
      int grow = rb + row;
      float4 v = make_float4(0.f, 0.f, 0.f, 0.f);
      if (grow < nrows)
        v = *(const float4*)(P + (size_t)grow * 128 + kc * 32 + k0);
      Rl[(k0 + 0) * 66 + row] = v.x;
      Rl[(k0 + 1) * 66 + row] = v.y;
      Rl[(k0 + 2) * 66 + row] = v.z;
      Rl[(k0 + 3) * 66 + row] = v.w;
    }
    __syncthreads();
    const float* Wp = W + (size_t)(kc * 32) * 128 + cb;
#pragma unroll 8
    for (int k = 0; k < 32; ++k) {
      float rv = Rl[k * 66 + l];
#pragma unroll
      for (int j = 0; j < 16; ++j) acc[j] = fmaf(rv, Wp[k * 128 + j], acc[j]);
    }
  }
  int row = rb + l;
  if (row < nrows) {
    float sa = 0.f, sd = 0.f;
#pragma unroll
    for (int j = 0; j < 16; ++j) {
      sa = fmaf(acc[j], attS[cb + j], sa);
      sd = fmaf(acc[j], attD[cb + j], sd);
    }
    a_srcb[(size_t)row * 8 + w] = f2bf(sa);
    a_dstb[(size_t)row * 8 + w] = f2bf(sd);
    unsigned pk[8];
#pragma unroll
    for (int m = 0; m < 8; ++m)
      pk[m] = (unsigned)f2bf(acc[2 * m]) | ((unsigned)f2bf(acc[2 * m + 1]) << 16);
    unsigned* xo = xb + (size_t)row * 64 + cb / 2;
    *(uint4*)(xo) = make_uint4(pk[0], pk[1], pk[2], pk[3]);
    *(uint4*)(xo + 4) = make_uint4(pk[4], pk[5], pk[6], pk[7]);
  }
}

// ---------------- K4: per-block sums ----------------
__global__ __launch_bounds__(256) void k_blocksum(const int* __restrict__ counts,
                                                  int* __restrict__ partials, int n) {
  __shared__ int sm[256];
  int t = threadIdx.x;
  int gid = blockIdx.x * 256 + t;
  sm[t] = gid < n ? counts[gid] : 0;
  __syncthreads();
  for (int s = 128; s > 0; s >>= 1) {
    if (t < s) sm[t] += sm[t + s];
    __syncthreads();
  }
  if (t == 0) partials[blockIdx.x] = sm[0];
}

// ---------------- K5: exclusive scan of partials ----------------
__global__ __launch_bounds__(512) void k_scanpartials(int* __restrict__ partials, int nb) {
  __shared__ int sm[512];
  int t = threadIdx.x;
  int v = t < nb ? partials[t] : 0;
  sm[t] = v;
  __syncthreads();
  for (int off = 1; off < 512; off <<= 1) {
    int u = (t >= off) ? sm[t - off] : 0;
    __syncthreads();
    sm[t] += u;
    __syncthreads();
  }
  if (t < nb) partials[t] = sm[t] - v;
}

// ---------------- K6: final exclusive scan -> offsets ----------------
__global__ __launch_bounds__(256) void k_scanfinal(const int* __restrict__ counts,
                                                   const int* __restrict__ partials,
                                                   int* __restrict__ offsets, int n) {
  __shared__ int sm[256];
  int t = threadIdx.x;
  int gid = blockIdx.x * 256 + t;
  int v = gid < n ? counts[gid] : 0;
  sm[t] = v;
  __syncthreads();
  for (int off = 1; off < 256; off <<= 1) {
    int u = (t >= off) ? sm[t - off] : 0;
    __syncthreads();
    sm[t] += u;
    __syncthreads();
  }
  int excl = partials[blockIdx.x] + sm[t] - v;
  if (gid < n) offsets[gid] = excl;
  if (gid == n - 1) offsets[n] = excl + v;
}

// ------- K7: asum = a_src[sv]+a_edge -> sorted 32B rec at offsets[dv]+rank[e] -----
// Grid-stride: scattered stores of iteration k drain under iteration k+1's work.
__global__ __launch_bounds__(256) void k_edgeprep(
    const float* __restrict__ EA, const float* __restrict__ Wedge,
    const float* __restrict__ attE, const int* __restrict__ src,
    const int* __restrict__ dst, const unsigned short* __restrict__ a_srcb,
    const int* __restrict__ offsets, const int* __restrict__ rank,
    unsigned* __restrict__ rec) {
  __shared__ float M[16][8];
  int t = threadIdx.x;
  if (t < 128) {
    int d = t >> 3, h = t & 7;
    float s = 0.f;
#pragma unroll
    for (int c = 0; c < 16; ++c)
      s = fmaf(Wedge[d * 128 + h * 16 + c], attE[h * 16 + c], s);
    M[d][h] = s;
  }
  __syncthreads();
  int stride = gridDim.x * 256;
  for (int e = blockIdx.x * 256 + t; e < EE; e += stride) {
    int sv = src[e], dv = dst[e];
    int rk = rank[e];
    int off = offsets[dv];          // 4 B gather from 400 KB (L2-resident)
    uint4 as4 = *(const uint4*)(a_srcb + (unsigned)sv * 8);
    float ea[16];
    const float4* ea4 = (const float4*)(EA + (size_t)e * 16);
#pragma unroll
    for (int i = 0; i < 4; ++i) {
      float4 v = ea4[i];
      ea[i * 4] = v.x; ea[i * 4 + 1] = v.y; ea[i * 4 + 2] = v.z; ea[i * 4 + 3] = v.w;
    }
    unsigned asu[4] = {as4.x, as4.y, as4.z, as4.w};
    unsigned pk[4];
#pragma unroll
    for (int m = 0; m < 4; ++m) {
      float s0 = 0.f, s1 = 0.f;
#pragma unroll
      for (int d = 0; d < 16; ++d) {
        s0 = fmaf(ea[d], M[d][2 * m], s0);
        s1 = fmaf(ea[d], M[d][2 * m + 1], s1);
      }
      s0 += bf_lo(asu[m]);
      s1 += bf_hi(asu[m]);
      pk[m] = (unsigned)f2bf(s0) | ((unsigned)f2bf(s1) << 16);
    }
    int pos = off + rk;
    unsigned* rp = rec + (size_t)pos * 8;   // 32 B sector-aligned record
    *(uint4*)(rp) = make_uint4(pk[0], pk[1], pk[2], pk[3]);
    *(uint4*)(rp + 4) = make_uint4((unsigned)sv, (unsigned)e, (unsigned)dv, 0u);
  }
}

// ---- K8: fused alpha + softmax + aggregation + node LN + EDGE OUT (pass 2) ------
// one wave per node. Pass 1: four 16-lane quarter-teams stream the segment,
// accumulating den + weighted x (only xb gathered). Pass 2: per-lane records
// (L2-hot) -> edge LN + linear + relu -> 4 B scatter to edge_out[e].
__global__ __launch_bounds__(512) void k_megaagg(
    const int* __restrict__ offsets, const unsigned* __restrict__ rec,
    const unsigned short* __restrict__ a_dstb, const unsigned* __restrict__ xb,
    const float* __restrict__ bias, const float* __restrict__ g,
    const float* __restrict__ b, const float* __restrict__ eg,
    const float* __restrict__ ebv_, const float* __restrict__ ew,
    const float* __restrict__ ebias, float* __restrict__ node_out,
    float* __restrict__ edge_out) {
  int w = threadIdx.x >> 6, l = threadIdx.x & 63;
  int n = blockIdx.x * 8 + w;
  if (n >= NN) return;
  int s = offsets[n], e = offsets[n + 1];
  int qt = l >> 4, ql = l & 15;
  int h = ql >> 1;
  int hsel = (ql >> 1) & 1;  // head's half within its packed word: h&1
  int hw = ql >> 2;          // u32 word index of head pair: h>>1
  float ad = us_bf(a_dstb[(unsigned)n * 8 + h]);
  float dn0 = 0.f, dn1 = 0.f, dn2 = 0.f, dn3 = 0.f;
  float acc[8] = {0.f, 0.f, 0.f, 0.f, 0.f, 0.f, 0.f, 0.f};
  int i = s + qt;
  for (; i + 12 < e; i += 16) {
    const unsigned* rA = rec + (size_t)i * 8;
    const unsigned* rB = rec + (size_t)(i + 4) * 8;
    const unsigned* rC = rec + (size_t)(i + 8) * 8;
    const unsigned* rD = rec + (size_t)(i + 12) * 8;
    unsigned auA = rA[hw]; int svA = (int)rA[4];
    unsigned auB = rB[hw]; int svB = (int)rB[4];
    unsigned auC = rC[hw]; int svC = (int)rC[4];
    unsigned auD = rD[hw]; int svD = (int)rD[4];
    uint4 xA = *(const uint4*)(xb + (unsigned)svA * 64 + ql * 4);
    uint4 xB = *(const uint4*)(xb + (unsigned)svB * 64 + ql * 4);
    uint4 xC = *(const uint4*)(xb + (unsigned)svC * 64 + ql * 4);
    uint4 xD = *(const uint4*)(xb + (unsigned)svD * 64 + ql * 4);
    float aA = hsel ? bf_hi(auA) : bf_lo(auA);
    float aB = hsel ? bf_hi(auB) : bf_lo(auB);
    float aC = hsel ? bf_hi(auC) : bf_lo(auC);
    float aD = hsel ? bf_hi(auD) : bf_lo(auD);
    float eA = __expf(lrelu02(aA + ad));
    float eB = __expf(lrelu02(aB + ad));
    float eC = __expf(lrelu02(aC + ad));
    float eD = __expf(lrelu02(aD + ad));
    dn0 += eA; dn1 += eB; dn2 += eC; dn3 += eD;
    acc[0] = fmaf(eA, bf_lo(xA.x), acc[0]); acc[1] = fmaf(eA, bf_hi(xA.x), acc[1]);
    acc[2] = fmaf(eA, bf_lo(xA.y), acc[2]); acc[3] = fmaf(eA, bf_hi(xA.y), acc[3]);
    acc[4] = fmaf(eA, bf_lo(xA.z), acc[4]); acc[5] = fmaf(eA, bf_hi(xA.z), acc[5]);
    acc[6] = fmaf(eA, bf_lo(xA.w), acc[6]); acc[7] = fmaf(eA, bf_hi(xA.w), acc[7]);
    acc[0] = fmaf(eB, bf_lo(xB.x), acc[0]); acc[1] = fmaf(eB, bf_hi(xB.x), acc[1]);
    acc[2] = fmaf(eB, bf_lo(xB.y), acc[2]); acc[3] = fmaf(eB, bf_hi(xB.y), acc[3]);
    acc[4] = fmaf(eB, bf_lo(xB.z), acc[4]); acc[5] = fmaf(eB, bf_hi(xB.z), acc[5]);
    acc[6] = fmaf(eB, bf_lo(xB.w), acc[6]); acc[7] = fmaf(eB, bf_hi(xB.w), acc[7]);
    acc[0] = fmaf(eC, bf_lo(xC.x), acc[0]); acc[1] = fmaf(eC, bf_hi(xC.x), acc[1]);
    acc[2] = fmaf(eC, bf_lo(xC.y), acc[2]); acc[3] = fmaf(eC, bf_hi(xC.y), acc[3]);
    acc[4] = fmaf(eC, bf_lo(xC.z), acc[4]); acc[5] = fmaf(eC, bf_hi(xC.z), acc[5]);
    acc[6] = fmaf(eC, bf_lo(xC.w), acc[6]); acc[7] = fmaf(eC, bf_hi(xC.w), acc[7]);
    acc[0] = fmaf(eD, bf_lo(xD.x), acc[0]); acc[1] = fmaf(eD, bf_hi(xD.x), acc[1]);
    acc[2] = fmaf(eD, bf_lo(xD.y), acc[2]); acc[3] = fmaf(eD, bf_hi(xD.y), acc[3]);
    acc[4] = fmaf(eD, bf_lo(xD.z), acc[4]); acc[5] = fmaf(eD, bf_hi(xD.z), acc[5]);
    acc[6] = fmaf(eD, bf_lo(xD.w), acc[6]); acc[7] = fmaf(eD, bf_hi(xD.w), acc[7]);
  }
  for (; i < e; i += 4) {
    const unsigned* rA = rec + (size_t)i * 8;
    unsigned auA = rA[hw]; int svA = (int)rA[4];
    uint4 xA = *(const uint4*)(xb + (unsigned)svA * 64 + ql * 4);
    float aA = hsel ? bf_hi(auA) : bf_lo(auA);
    float eA = __expf(lrelu02(aA + ad));
    dn0 += eA;
    acc[0] = fmaf(eA, bf_lo(xA.x), acc[0]); acc[1] = fmaf(eA, bf_hi(xA.x), acc[1]);
    acc[2] = fmaf(eA, bf_lo(xA.y), acc[2]); acc[3] = fmaf(eA, bf_hi(xA.y), acc[3]);
    acc[4] = fmaf(eA, bf_lo(xA.z), acc[4]); acc[5] = fmaf(eA, bf_hi(xA.z), acc[5]);
    acc[6] = fmaf(eA, bf_lo(xA.w), acc[6]); acc[7] = fmaf(eA, bf_hi(xA.w), acc[7]);
  }
  float den = (dn0 + dn1) + (dn2 + dn3);
  den += __shfl_xor(den, 16);
  den += __shfl_xor(den, 32);
#pragma unroll
  for (int j = 0; j < 8; ++j) {
    acc[j] += __shfl_xor(acc[j], 16);
    acc[j] += __shfl_xor(acc[j], 32);
  }
  float inv = 1.f / (den + 1e-16f);
  int c0 = ql * 8;
  float4 bv0 = *(const float4*)(bias + c0);
  float4 bv1 = *(const float4*)(bias + c0 + 4);
  acc[0] = acc[0] * inv + bv0.x;
  acc[1] = acc[1] * inv + bv0.y;
  acc[2] = acc[2] * inv + bv0.z;
  acc[3] = acc[3] * inv + bv0.w;
  acc[4] = acc[4] * inv + bv1.x;
  acc[5] = acc[5] * inv + bv1.y;
  acc[6] = acc[6] * inv + bv1.z;
  acc[7] = acc[7] * inv + bv1.w;
  float sum = ((acc[0] + acc[1]) + (acc[2] + acc[3])) +
              ((acc[4] + acc[5]) + (acc[6] + acc[7]));
#pragma unroll
  for (int off = 1; off < 64; off <<= 1) sum += __shfl_xor(sum, off);
  float mu = sum * (1.f / 512.f);  // cols duplicated across 4 quarter-teams
  float d[8], ss = 0.f;
#pragma unroll
  for (int j = 0; j < 8; ++j) { d[j] = acc[j] - mu; ss += d[j] * d[j]; }
#pragma unroll
  for (int off = 1; off < 64; off <<= 1) ss += __shfl_xor(ss, off);
  float r = rsqrtf(ss * (1.f / 512.f) + LN_EPS);
  if (qt == 0) {
    float4 gv0 = *(const float4*)(g + c0);
    float4 gv1 = *(const float4*)(g + c0 + 4);
    float4 bb0 = *(const float4*)(b + c0);
    float4 bb1 = *(const float4*)(b + c0 + 4);
    float y[8];
    y[0] = d[0] * r * gv0.x + bb0.x;
    y[1] = d[1] * r * gv0.y + bb0.y;
    y[2] = d[2] * r * gv0.z + bb0.z;
    y[3] = d[3] * r * gv0.w + bb0.w;
    y[4] = d[4] * r * gv1.x + bb1.x;
    y[5] = d[5] * r * gv1.y + bb1.y;
    y[6] = d[6] * r * gv1.z + bb1.z;
    y[7] = d[7] * r * gv1.w + bb1.w;
#pragma unroll
    for (int j = 0; j < 8; ++j) y[j] = y[j] >= 0.f ? y[j] : 0.01f * y[j];
    float* no = node_out + (size_t)n * 128 + c0;
    *(float4*)(no) = make_float4(y[0], y[1], y[2], y[3]);
    *(float4*)(no + 4) = make_float4(y[4], y[5], y[6], y[7]);
  }
  // ---------- pass 2: edge outputs for this node's segment (rec is L2-hot) ------
  float invs[8];
#pragma unroll
  for (int hh = 0; hh < 8; ++hh) invs[hh] = __shfl(inv, hh * 2);
  uint4 adu4 = *(const uint4*)(a_dstb + (unsigned)n * 8);
  unsigned adu[4] = {adu4.x, adu4.y, adu4.z, adu4.w};
  float gw[8];
  float bsum = ebias[0];
#pragma unroll
  for (int hh = 0; hh < 8; ++hh) {
    float ewv = ew[hh];
    gw[hh] = eg[hh] * ewv;
    bsum += ebv_[hh] * ewv;
  }
  for (int i2 = s + l; i2 < e; i2 += 64) {
    const unsigned* rp = rec + (size_t)i2 * 8;
    uint4 as4 = *(const uint4*)(rp);
    unsigned eidx = rp[5];
    unsigned asu[4] = {as4.x, as4.y, as4.z, as4.w};
    float p[8];
#pragma unroll
    for (int m = 0; m < 4; ++m) {
      float a0 = lrelu02(bf_lo(asu[m]) + bf_lo(adu[m]));
      float a1 = lrelu02(bf_hi(asu[m]) + bf_hi(adu[m]));
      p[2 * m] = __expf(a0) * invs[2 * m];
      p[2 * m + 1] = __expf(a1) * invs[2 * m + 1];
    }
    float pm = 0.f;
#pragma unroll
    for (int hh = 0; hh < 8; ++hh) pm += p[hh];
    pm *= 0.125f;
    float var = 0.f, dot = 0.f;
#pragma unroll
    for (int hh = 0; hh < 8; ++hh) {
      float dd = p[hh] - pm;
      var += dd * dd;
      dot += dd * gw[hh];
    }
    var *= 0.125f;
    float rr = rsqrtf(var + LN_EPS);
    float o = dot * rr + bsum;
    edge_out[eidx] = fmaxf(o, 0.f);
  }
}

extern "C" void kernel_launch(void* const* d_in, const int* in_sizes, int n_in,
                              void* d_out, int out_size, void* d_ws, size_t ws_size,
                              hipStream_t stream) {
  const void* edge_index = d_in[0];
  const float* point_attr = (const float*)d_in[1];
  const float* edge_attr = (const float*)d_in[2];
  const float* W = (const float*)d_in[3];
  const float* att_src = (const float*)d_in[4];
  const float* att_dst = (const float*)d_in[5];
  const float* W_edge = (const float*)d_in[6];
  const float* att_edge = (const float*)d_in[7];
  const float* bias = (const float*)d_in[8];
  const float* ln_node_g = (const float*)d_in[9];
  const float* ln_node_b = (const float*)d_in[10];
  const float* ln_edge_g = (const float*)d_in[11];
  const float* ln_edge_b = (const float*)d_in[12];
  const float* edge_w = (const float*)d_in[13];
  const float* edge_b = (const float*)d_in[14];

  char* wsb = (char*)d_ws;
  size_t o = 0;
  auto take = [&](size_t bytes) -> void* {
    void* p = wsb + o;
    o += (bytes + 255) & ~(size_t)255;
    return p;
  };
  int* flag = (int*)take(4);
  int* idx32 = (int*)take((size_t)2 * EE * 4);
  unsigned* xb = (unsigned*)take((size_t)NN * 128 * 2);
  unsigned short* a_srcb = (unsigned short*)take((size_t)NN * 8 * 2);
  unsigned short* a_dstb = (unsigned short*)take((size_t)NN * 8 * 2);
  int* counts = (int*)take((size_t)NN * 4);
  int* offsets = (int*)take((size_t)(NN + 1) * 4);
  int* rank = (int*)take((size_t)EE * 4);
  int* partials = (int*)take(512 * 4);
  unsigned* rec = (unsigned*)take((size_t)EE * 32);     // 32 B sorted records

  const int* srcp = idx32;
  const int* dstp = idx32 + EE;
  float* node_out = (float*)d_out;
  float* edge_out = node_out + (size_t)NN * 128;

  int nb_scan = (NN + 255) / 256;  // 391

  hipMemsetAsync(counts, 0, (size_t)NN * 4, stream);

  k_detect<<<1, 64, 0, stream>>>(edge_index, flag);
  k_convert_hist<<<(EE + 255) / 256, 256, 0, stream>>>(edge_index, flag, idx32,
                                                       counts, rank);
  k_gemm_node<<<(NN + 63) / 64, 512, 0, stream>>>(point_attr, W, att_src, att_dst,
                                                  xb, a_srcb, a_dstb, NN);
  k_blocksum<<<nb_scan, 256, 0, stream>>>(counts, partials, NN);
  k_scanpartials<<<1, 512, 0, stream>>>(partials, nb_scan);
  k_scanfinal<<<nb_scan, 256, 0, stream>>>(counts, partials, offsets, NN);
  k_edgeprep<<<2048, 256, 0, stream>>>(edge_attr, W_edge, att_edge, srcp, dstp,
                                       a_srcb, offsets, rank, rec);
  k_megaagg<<<(NN + 7) / 8, 512, 0, stream>>>(offsets, rec, a_dstb, xb, bias,
                                              ln_node_g, ln_node_b, ln_edge_g,
                                              ln_edge_b, edge_w, edge_b,
                                              node_out, edge_out);
}